// Round 5
// baseline (411.070 us; speedup 1.0000x reference)
//
#include <hip/hip_runtime.h>

#define CH    256
#define NTOK  2304
#define MATSZ (CH * NTOK)   // 589824 elements per (b, matrix)

typedef __bf16 bf16x8 __attribute__((ext_vector_type(8)));
typedef float  f4v    __attribute__((ext_vector_type(4)));
typedef float  f16v   __attribute__((ext_vector_type(16)));
typedef unsigned int u32x4 __attribute__((ext_vector_type(4)));

__device__ __forceinline__ unsigned short f2bf(float f) {
    union { float f; unsigned int i; } c;
    c.f = f;
    unsigned int x = c.i;
    x += 0x7fffu + ((x >> 16) & 1u);   // round-to-nearest-even
    return (unsigned short)(x >> 16);
}

__device__ __forceinline__ bf16x8 cvt8(const float* p) {
    union { bf16x8 v; unsigned short s[8]; } u;
#pragma unroll
    for (int i = 0; i < 8; ++i) u.s[i] = f2bf(p[i]);
    return u.v;
}

// ---------------------------------------------------------------------------
// 64x64-tiled transpose + fp32->bf16 (unchanged — HW-verified)
// ---------------------------------------------------------------------------
__global__ __launch_bounds__(256) void tpose_k(
    const float* __restrict__ inL,
    const float* __restrict__ inR,
    unsigned short* __restrict__ out, int R, int Ccols)
{
    __shared__ unsigned short tile[64][72];
    int mat = blockIdx.y;
    const float* in = (mat >= 8 ? inR : inL) + (size_t)(mat & 7) * MATSZ;
    unsigned short* o = out + (size_t)mat * MATSZ;
    int tC = Ccols >> 6;
    int r0 = (blockIdx.x / tC) << 6;
    int c0 = (blockIdx.x % tC) << 6;
    int t = threadIdx.x;
    int col = t & 63, rs = t >> 6;
#pragma unroll
    for (int i = 0; i < 16; ++i) {
        int row = rs + i * 4;
        tile[row][col] = f2bf(in[(size_t)(r0 + row) * Ccols + c0 + col]);
    }
    __syncthreads();
#pragma unroll
    for (int i = 0; i < 16; ++i) {
        int crow = rs + i * 4;
        o[(size_t)(c0 + crow) * R + r0 + col] = tile[col][crow];
    }
}

// ---------------------------------------------------------------------------
// Projection (unchanged — HW-verified)
// ---------------------------------------------------------------------------
__global__ __launch_bounds__(256, 2) void proj_k(
    const unsigned short* __restrict__ XT,   // [2][8][2304][256] bf16
    const float* __restrict__ Wq_, const float* __restrict__ Wk_,
    const float* __restrict__ bq_, const float* __restrict__ bk_,
    const float* __restrict__ gq_, const float* __restrict__ gk_,
    const float* __restrict__ beq_, const float* __restrict__ bek_,
    const float* __restrict__ mq_, const float* __restrict__ mk_,
    const float* __restrict__ vq_, const float* __restrict__ vk_,
    unsigned short* __restrict__ Yout)       // [4][8][MATSZ] bf16
{
    __shared__ __align__(16) unsigned short Xs[64][264];
    int pb = blockIdx.y;
    int p = pb >> 3, b = pb & 7;
    int s = p & 1, br = p >> 1;
    const unsigned short* X = XT + (size_t)(s * 8 + b) * MATSZ;
    const float* W  = br ? Wk_ : Wq_;
    const float* bb = br ? bk_ : bq_;
    const float* gg = br ? gk_ : gq_;
    const float* be = br ? bek_ : beq_;
    const float* mm = br ? mk_ : mq_;
    const float* vv = br ? vk_ : vq_;
    unsigned short* Yo = Yout + (size_t)pb * MATSZ;

    int ot = blockIdx.x & 3, pt = blockIdx.x >> 2;
    int o0 = ot * 64, pos0 = pt * 64;
    int t = threadIdx.x;
    int w = t >> 6, lane = t & 63;
    int l15 = lane & 15, quad = lane >> 4;

    {   // stage XT tile: 64 pos-rows x 256 c
        int r = t >> 2, cq = (t & 3) << 6;
        const unsigned short* src = X + (size_t)(pos0 + r) * CH + cq;
        unsigned short* dst = &Xs[r][cq];
#pragma unroll
        for (int k = 0; k < 8; ++k)
            *(u32x4*)(dst + k * 8) = *(const u32x4*)(src + k * 8);
    }
    bf16x8 wf[8];
    {
        const float* wp = W + (size_t)(o0 + w * 16 + l15) * CH + quad * 8;
#pragma unroll
        for (int kc = 0; kc < 8; ++kc)
            wf[kc] = cvt8(wp + kc * 32);
    }
    __syncthreads();

    f4v zero4 = {0.f, 0.f, 0.f, 0.f};
    f4v acc[4] = {zero4, zero4, zero4, zero4};
#pragma unroll
    for (int kc = 0; kc < 8; ++kc) {
#pragma unroll
        for (int ct = 0; ct < 4; ++ct) {
            bf16x8 xb = *(const bf16x8*)(&Xs[ct * 16 + l15][kc * 32 + quad * 8]);
            acc[ct] = __builtin_amdgcn_mfma_f32_16x16x32_bf16(wf[kc], xb, acc[ct], 0, 0, 0);
        }
    }
#pragma unroll
    for (int r = 0; r < 4; ++r) {
        int o = o0 + w * 16 + quad * 4 + r;
        float scale = gg[o] * rsqrtf(vv[o] + 1e-5f);
        float shift = (bb[o] - mm[o]) * scale + be[o];
#pragma unroll
        for (int ct = 0; ct < 4; ++ct) {
            float val = acc[ct][r] * scale + shift;
            Yo[(size_t)o * NTOK + pos0 + ct * 16 + l15] = f2bf(val);
        }
    }
}

// ---------------------------------------------------------------------------
// Fused attention R5 = R4 compute (32x32x16 MFMA, 2x FLOP per LDS byte) +
// R2 staging (register-prefetch + swizzled ds_write).
//
// R4 post-mortem: global_load_lds + barrier drains vmcnt(0) EVERY tile ->
// L2 round-trip (~300-600cy) serial on the critical path. R2's structure
// prefetches tile kt+1 into REGISTERS right after the stage barrier; the
// loads get the whole tile compute (~1500cy) to land; only a fast lgkm
// drain of ds_writes sits before the stage barrier.
//
// LDS layouts (HW-verified R2/R4, byte-identical):
//   Ks [64 key][512B]  phys = key*512 + (off ^ ((key&7)<<4))
//   Vs [256 ch][128B]  phys = ch*128  + (off ^ ((ch&7)<<4))
//   Pb [64 q ][128B]   phys = q*128   + (off ^ ((q&7)<<4))
// Staging write map (R2-verified constants): flat f = k*4096 + t*16;
//   K: key = k*8+(t>>5)  -> kdst = Ks + (t*16 ^ ((t>>5&7)<<4)) + k*4096
//   V: ch  = k*32+(t>>3) -> vdst = Vs + (t*16 ^ ((t>>3&7)<<4)) + k*4096
// Compute/Pb/epilogue: unchanged from R4 (HW-verified).
// ---------------------------------------------------------------------------
__global__ __launch_bounds__(256, 2) void attn_k(
    const unsigned short* __restrict__ Y,    // [4][8][MATSZ] projections bf16
    const unsigned short* __restrict__ VT,   // [2][8][256][2304] bf16
    float* __restrict__ out)                 // [2][8][MATSZ] fp32
{
    __shared__ __align__(16) unsigned char lds[74240];
    unsigned char* Ks = lds;                    // 32768
    unsigned char* Vs = lds + 32768;            // 32768
    unsigned char* Pb = lds + 65536;            // 8192
    float*         Ls = (float*)(lds + 73728);  // [4][32] f32

    int bid = blockIdx.x;
    int wg = (bid & 7) * 72 + (bid >> 3);   // XCD swizzle (576 = 8*72, bijective)
    int qt = wg % 36;
    int ab = wg / 36;
    int a = ab >> 3, b = ab & 7;
    const unsigned short* Qp = Y + (size_t)(a * 8 + b) * MATSZ;        // q(l)/q(r)
    const unsigned short* Kp = Y + (size_t)((3 - a) * 8 + b) * MATSZ;  // k(r)/k(l)
    const unsigned short* Vp = VT + (size_t)((1 - a) * 8 + b) * MATSZ;
    float* Op = out + (size_t)ab * MATSZ;

    int t = threadIdx.x;
    int w = t >> 6, lane = t & 63;
    int l31 = lane & 31, h = lane >> 5;
    int qb = w >> 1;             // q-block (QK^T and PV)
    int kb = w & 1;              // key-block (QK^T)
    int chh = w & 1;             // channel-half (PV)
    int rxor = (l31 & 7) << 4;   // read-side swizzle (row&7 == l31&7 everywhere)

    // staging: R2-verified register-prefetch maps
    const unsigned short* ksrc0 = Kp + t * 8;                          // + kt*16384 + k*2048 (shorts)
    const unsigned short* vsrc0 = Vp + (size_t)(t >> 3) * NTOK + ((t & 7) << 3);  // + kt*64 + k*32*NTOK
    char* kdst = (char*)Ks + ((t * 16) ^ (((t >> 5) & 7) << 4));       // + k*4096
    char* vdst = (char*)Vs + ((t * 16) ^ (((t >> 3) & 7) << 4));       // + k*4096

    // Q fragments in registers: rows qt*64 + qb*32 + l31, A-frag k = h*8+j
    bf16x8 qf[16];
    {
        const unsigned short* qp = Qp + (size_t)(qt * 64 + qb * 32 + l31) * CH + h * 8;
#pragma unroll
        for (int ks = 0; ks < 16; ++ks)
            qf[ks] = *(const bf16x8*)(qp + ks * 16);
    }

    f16v acc_o[4];
#pragma unroll
    for (int c = 0; c < 4; ++c)
#pragma unroll
        for (int r = 0; r < 16; ++r) acc_o[c][r] = 0.f;
    float l_acc[16];
#pragma unroll
    for (int r = 0; r < 16; ++r) l_acc[r] = 0.f;

    // preload tile kt=0 into registers
    u32x4 kreg[8], vreg[8];
#pragma unroll
    for (int k = 0; k < 8; ++k) kreg[k] = *(const u32x4*)(ksrc0 + k * 2048);
#pragma unroll
    for (int k = 0; k < 8; ++k) vreg[k] = *(const u32x4*)(vsrc0 + (size_t)k * 32 * NTOK);

    for (int kt = 0; kt < 36; ++kt) {
        __syncthreads();   // readers of tile kt-1 done (Ks, Vs, Pb)
#pragma unroll
        for (int k = 0; k < 8; ++k) *(u32x4*)(kdst + k * 4096) = kreg[k];
#pragma unroll
        for (int k = 0; k < 8; ++k) *(u32x4*)(vdst + k * 4096) = vreg[k];
        __syncthreads();   // staged tile visible

        if (kt < 35) {     // prefetch kt+1; lands during QK^T+PV (~1500cy)
            const unsigned short* kn = ksrc0 + (size_t)(kt + 1) * 16384;
            const unsigned short* vn = vsrc0 + (size_t)(kt + 1) * 64;
#pragma unroll
            for (int k = 0; k < 8; ++k) kreg[k] = *(const u32x4*)(kn + k * 2048);
#pragma unroll
            for (int k = 0; k < 8; ++k) vreg[k] = *(const u32x4*)(vn + (size_t)k * 32 * NTOK);
        }

        // ---- QK^T: S[qb*32..+32][kb*32..+32], 16 k-steps
        f16v accs;
#pragma unroll
        for (int r = 0; r < 16; ++r) accs[r] = 0.f;
        const unsigned char* krow = Ks + ((kb * 32 + l31) << 9);
#pragma unroll
        for (int ks = 0; ks < 16; ++ks) {
            bf16x8 kf = *(const bf16x8*)(krow + ((ks * 32 + h * 16) ^ rxor));
            accs = __builtin_amdgcn_mfma_f32_32x32x16_bf16(qf[ks], kf, accs, 0, 0, 0);
        }
        // ---- exp, partial row-sums, P write (C-layout row=(r&3)+8*(r>>2)+4h)
#pragma unroll
        for (int r = 0; r < 16; ++r) {
            float pe = __expf(accs[r] * (1.0f / 256.0f));
            l_acc[r] += pe;
            int row = (r & 3) + 8 * (r >> 2) + 4 * h;   // q within qb*32
            int q = qb * 32 + row;
            *(__bf16*)(Pb + q * 128 + ((kb * 64 + l31 * 2) ^ ((row & 7) << 4))) = (__bf16)pe;
        }
        __syncthreads();   // P(kt) visible to all waves

        // ---- PV: O[qb*32..+32][chh*128..+128]
#pragma unroll
        for (int ks2 = 0; ks2 < 4; ++ks2) {
            bf16x8 pf = *(const bf16x8*)(Pb + ((qb * 32 + l31) << 7)
                                       + ((ks2 * 32 + h * 16) ^ rxor));
#pragma unroll
            for (int chb = 0; chb < 4; ++chb) {
                int ch = chh * 128 + chb * 32 + l31;
                bf16x8 vf = *(const bf16x8*)(Vs + (ch << 7)
                                           + ((ks2 * 32 + h * 16) ^ rxor));
                acc_o[chb] = __builtin_amdgcn_mfma_f32_32x32x16_bf16(pf, vf, acc_o[chb], 0, 0, 0);
            }
        }
    }

    // ---- row-sum finalize: reduce over the 32 key-lanes (within each half)
#pragma unroll
    for (int r = 0; r < 16; ++r) {
        float rs = l_acc[r];
        rs += __shfl_xor(rs, 1, 64);
        rs += __shfl_xor(rs, 2, 64);
        rs += __shfl_xor(rs, 4, 64);
        rs += __shfl_xor(rs, 8, 64);
        rs += __shfl_xor(rs, 16, 64);
        l_acc[r] = rs;
    }
    if (l31 == 0) {   // lanes 0 and 32 publish their half's 16 rows
#pragma unroll
        for (int r = 0; r < 16; ++r) {
            int row = (r & 3) + 8 * (r >> 2) + 4 * h;
            Ls[w * 32 + row] = l_acc[r];
        }
    }
    __syncthreads();   // Ls visible; also fences last PV reads before Ot reuse
    float l_tot[16];
#pragma unroll
    for (int r = 0; r < 16; ++r) {
        int row = (r & 3) + 8 * (r >> 2) + 4 * h;
        l_tot[r] = Ls[w * 32 + row] + Ls[(w ^ 1) * 32 + row];  // kb0 + kb1
    }

    // ---- epilogue: normalize, swizzled fp32 transpose, coalesced stores
    float* Ot = (float*)lds;   // [256 ch][64 q] f32, dword-XOR ((c&7)<<2)
#pragma unroll
    for (int chb = 0; chb < 4; ++chb) {
        int c = chh * 128 + chb * 32 + l31;
        int cx = (c & 7) << 2;
#pragma unroll
        for (int rr = 0; rr < 4; ++rr) {
            f4v v4;
#pragma unroll
            for (int i = 0; i < 4; ++i)
                v4[i] = acc_o[chb][rr * 4 + i] / l_tot[rr * 4 + i];
            int q0 = qb * 32 + rr * 8 + h * 4;   // rows rr*8+{0..3}+4h consecutive
            *(f4v*)(Ot + c * 64 + (q0 ^ cx)) = v4;
        }
    }
    __syncthreads();
#pragma unroll
    for (int p = 0; p < 16; ++p) {
        int c = p * 16 + (t >> 4);
        int q = (t & 15) * 4;
        f4v v4 = *(const f4v*)(Ot + c * 64 + (q ^ ((c & 7) << 2)));
        *(f4v*)(Op + (size_t)c * NTOK + qt * 64 + q) = v4;
    }
}

// ---------------------------------------------------------------------------
extern "C" void kernel_launch(void* const* d_in, const int* in_sizes, int n_in,
                              void* d_out, int out_size, void* d_ws, size_t ws_size,
                              hipStream_t stream) {
    (void)in_sizes; (void)n_in; (void)out_size; (void)ws_size;
    const float* feaL  = (const float*)d_in[0];
    const float* feaR  = (const float*)d_in[1];
    const float* Wq    = (const float*)d_in[2];
    const float* bq    = (const float*)d_in[3];
    const float* gq    = (const float*)d_in[4];
    const float* betaq = (const float*)d_in[5];
    const float* mq    = (const float*)d_in[6];
    const float* vq    = (const float*)d_in[7];
    const float* Wk    = (const float*)d_in[8];
    const float* bk    = (const float*)d_in[9];
    const float* gk    = (const float*)d_in[10];
    const float* betak = (const float*)d_in[11];
    const float* mk    = (const float*)d_in[12];
    const float* vk    = (const float*)d_in[13];

    // workspace (bf16): XT/VT alias 16*MATSZ (18.9MB) | Y 32*MATSZ (37.7MB)
    unsigned short* XT = (unsigned short*)d_ws;   // reused as VT after proj
    unsigned short* VT = XT;
    unsigned short* Yb = XT + (size_t)16 * MATSZ;
    float* out = (float*)d_out;   // fp32: reference output dtype

    dim3 blk(256);
    // XT[s][b][pos][c] = fea[b][c][pos]
    tpose_k<<<dim3(144, 16), blk, 0, stream>>>(feaL, feaR, XT, 256, 2304);
    proj_k<<<dim3(144, 32), blk, 0, stream>>>(XT, Wq, Wk, bq, bk, gq, gk,
                                              betaq, betak, mq, mk, vq, vk, Yb);
    // VT[s][b][c][n] = fea_flat[n*256+c]
    tpose_k<<<dim3(144, 16), blk, 0, stream>>>(feaL, feaR, VT, 2304, 256);
    attn_k<<<dim3(576), blk, 0, stream>>>(Yb, VT, out);
}